// Round 2
// baseline (1080.975 us; speedup 1.0000x reference)
//
#include <hip/hip_runtime.h>
#include <hip/hip_fp16.h>
#include <cstdint>

typedef _Float16 f16;
typedef __attribute__((ext_vector_type(8))) _Float16 half8;
typedef __attribute__((ext_vector_type(4))) float floatx4;

#define CC 1024
#define DD 128
#define RRR 64
#define BBATCH 4
#define NNN 4096   // H*W

// ---------------- GEMM: C[M,N] = A[M,K] * B[N,K]^T  (f16 in, f32 acc) ----------------
#define BM 128
#define BN 128
#define BK 64

__device__ __forceinline__ void gl_lds16(const void* g, void* l) {
  __builtin_amdgcn_global_load_lds(
      (__attribute__((address_space(1))) void*)(uintptr_t)g,
      (__attribute__((address_space(3))) void*)l, 16, 0, 0);
}

// EPI: 0 = f32 out, no bias | 1 = f16 out + row bias | 2 = f16 out + col bias | 3 = f16 sigmoid
template<int EPI>
__global__ __launch_bounds__(256)
void gemm_bt(const f16* __restrict__ A, const f16* __restrict__ Bp, void* __restrict__ Cout,
             const float* __restrict__ bias, int M, int N, int K)
{
  __shared__ __align__(16) f16 As[BM * BK];
  __shared__ __align__(16) f16 Bs[BN * BK];
  const int tid  = threadIdx.x;
  const int lane = tid & 63;
  const int wave = tid >> 6;
  const int m0 = blockIdx.y * BM;
  const int n0 = blockIdx.x * BN;
  const int wm = (wave >> 1) * 64;
  const int wn = (wave & 1) * 64;

  floatx4 acc[4][4];
#pragma unroll
  for (int i = 0; i < 4; ++i)
#pragma unroll
    for (int j = 0; j < 4; ++j)
      acc[i][j] = (floatx4){0.f, 0.f, 0.f, 0.f};

  const int srow = lane >> 3;          // 0..7 row within 8-row chunk
  const int skof = (lane & 7) * 8;     // k elem offset (16B granules)
  const f16* aB = A  + (size_t)m0 * K;
  const f16* bB = Bp + (size_t)n0 * K;

  const int quad = lane >> 4;          // 0..3
  const int r16  = lane & 15;

  for (int k0 = 0; k0 < K; k0 += BK) {
    // stage A(128x64) and B(128x64) tiles: wave-uniform LDS base + lane*16B
#pragma unroll
    for (int r = 0; r < 4; ++r) {
      const int row = (r * 4 + wave) * 8 + srow;
      gl_lds16(aB + (size_t)row * K + k0 + skof, As + row * BK + skof);
      gl_lds16(bB + (size_t)row * K + k0 + skof, Bs + row * BK + skof);
    }
    __syncthreads();

#pragma unroll
    for (int kk = 0; kk < BK; kk += 32) {
      half8 af[4], bfr[4];
#pragma unroll
      for (int i = 0; i < 4; ++i)
        af[i] = *(const half8*)(As + (wm + i * 16 + r16) * BK + kk + quad * 8);
#pragma unroll
      for (int j = 0; j < 4; ++j)
        bfr[j] = *(const half8*)(Bs + (wn + j * 16 + r16) * BK + kk + quad * 8);
#pragma unroll
      for (int i = 0; i < 4; ++i)
#pragma unroll
        for (int j = 0; j < 4; ++j)
          acc[i][j] = __builtin_amdgcn_mfma_f32_16x16x32_f16(af[i], bfr[j], acc[i][j], 0, 0, 0);
    }
    __syncthreads();
  }

  // epilogue: C/D layout col=lane&15, row=quad*4+reg (dtype-independent, m121/m124)
#pragma unroll
  for (int i = 0; i < 4; ++i) {
#pragma unroll
    for (int r = 0; r < 4; ++r) {
      const int row = m0 + wm + i * 16 + quad * 4 + r;
#pragma unroll
      for (int j = 0; j < 4; ++j) {
        const int col = n0 + wn + j * 16 + r16;
        float v = acc[i][j][r];
        if constexpr (EPI == 0) {
          ((float*)Cout)[(size_t)row * N + col] = v;
        } else if constexpr (EPI == 1) {
          ((f16*)Cout)[(size_t)row * N + col] = (f16)(v + bias[row]);
        } else if constexpr (EPI == 2) {
          ((f16*)Cout)[(size_t)row * N + col] = (f16)(v + bias[col]);
        } else {
          ((f16*)Cout)[(size_t)row * N + col] = (f16)(1.0f / (1.0f + __expf(-v)));
        }
      }
    }
  }
}

// ---------------- transpose + f32->f16: in[rows][cols] f32 -> out[cols][rows] f16 ----------------
__global__ __launch_bounds__(256)
void transpose_cvt(const float* __restrict__ in, f16* __restrict__ out, int rows, int cols)
{
  __shared__ float tile[32][33];
  const int c0 = blockIdx.y * 32;
  const int n0 = blockIdx.x * 32;
  const int tx = threadIdx.x & 31;
  const int ty = threadIdx.x >> 5;   // 0..7
#pragma unroll
  for (int r = 0; r < 32; r += 8)
    tile[ty + r][tx] = in[(size_t)(c0 + ty + r) * cols + n0 + tx];
  __syncthreads();
#pragma unroll
  for (int r = 0; r < 32; r += 8)
    out[(size_t)(n0 + ty + r) * rows + c0 + tx] = (f16)tile[tx][ty + r];
}

// ---------------- f32 -> f16 elementwise ----------------
__global__ __launch_bounds__(256)
void cvt_f16(const float* __restrict__ in, f16* __restrict__ out, int n)
{
  int i = blockIdx.x * 256 + threadIdx.x;
  if (i < n) out[i] = (f16)in[i];
}

// ---------------- per-row mean + max over ncols ----------------
__global__ __launch_bounds__(256)
void rowreduce(const float* __restrict__ X, float* __restrict__ avg, float* __restrict__ mx, int ncols)
{
  const int row = blockIdx.x;
  const float4* p = (const float4*)(X + (size_t)row * ncols);
  float s = 0.f, m = -3.402823466e38f;
  for (int i = threadIdx.x; i < ncols / 4; i += 256) {
    float4 v = p[i];
    s += v.x + v.y + v.z + v.w;
    m = fmaxf(m, fmaxf(fmaxf(v.x, v.y), fmaxf(v.z, v.w)));
  }
#pragma unroll
  for (int o = 32; o > 0; o >>= 1) {
    s += __shfl_down(s, o);
    m = fmaxf(m, __shfl_down(m, o));
  }
  __shared__ float ss[4], sm[4];
  if ((threadIdx.x & 63) == 0) { ss[threadIdx.x >> 6] = s; sm[threadIdx.x >> 6] = m; }
  __syncthreads();
  if (threadIdx.x == 0) {
    s = ss[0] + ss[1] + ss[2] + ss[3];
    m = fmaxf(fmaxf(sm[0], sm[1]), fmaxf(sm[2], sm[3]));
    avg[row] = s / (float)ncols;
    mx[row] = m;
  }
}

// ---------------- CBAM MLP gate (one block per batch) ----------------
__global__ __launch_bounds__(256)
void mlp_gate(const float* __restrict__ avg, const float* __restrict__ mxv,
              const float* __restrict__ W1 /*[64][1024]*/, const float* __restrict__ W2 /*[1024][64]*/,
              float* __restrict__ gate)
{
  __shared__ float h[RRR];
  const int t = threadIdx.x;
  if (t < RRR) {
    const float* w = W1 + t * CC;
    float sa = 0.f, sm = 0.f;
    for (int c = 0; c < CC; ++c) { float wv = w[c]; sa += wv * avg[c]; sm += wv * mxv[c]; }
    h[t] = fmaxf(sa, 0.f) + fmaxf(sm, 0.f);
  }
  __syncthreads();
  for (int c = t; c < CC; c += 256) {
    float s = 0.f;
    for (int r = 0; r < RRR; ++r) s += W2[c * RRR + r] * h[r];
    gate[c] = 1.0f / (1.0f + __expf(-s));
  }
}

// ---------------- apply gate in place: out[c][n] *= gate[c] ----------------
__global__ __launch_bounds__(256)
void scale_out(float* __restrict__ out, const float* __restrict__ gate)
{
  size_t i = (size_t)blockIdx.x * 256 + threadIdx.x;   // over C*N/4
  float4* p = (float4*)out;
  const float g = gate[(i * 4) >> 12];                 // N = 4096 = 2^12
  float4 v = p[i];
  v.x *= g; v.y *= g; v.z *= g; v.w *= g;
  p[i] = v;
}

// ---------------- launch ----------------
extern "C" void kernel_launch(void* const* d_in, const int* in_sizes, int n_in,
                              void* d_out, int out_size, void* d_ws, size_t ws_size,
                              hipStream_t stream)
{
  const float* x    = (const float*)d_in[0];
  const float* x1   = (const float*)d_in[1];
  const float* Wq   = (const float*)d_in[2];
  const float* bq   = (const float*)d_in[3];
  const float* Wk   = (const float*)d_in[4];
  const float* bk   = (const float*)d_in[5];
  const float* Wv   = (const float*)d_in[6];
  const float* bv   = (const float*)d_in[7];
  const float* Wca1 = (const float*)d_in[8];
  const float* Wca2 = (const float*)d_in[9];
  float* out = (float*)d_out;

  char* ws = (char*)d_ws;
  size_t off = 0;
  auto alloc = [&](size_t bytes) { void* p = ws + off; off += (bytes + 255) & ~255ULL; return p; };

  f16* Wqb  = (f16*)alloc((size_t)DD * CC * 2);
  f16* Wkb  = (f16*)alloc((size_t)DD * CC * 2);
  f16* Wvb  = (f16*)alloc((size_t)CC * CC * 2);
  f16* xTb  = (f16*)alloc((size_t)NNN * CC * 2);   // per-batch, reused
  f16* x1Tb = (f16*)alloc((size_t)NNN * CC * 2);
  f16* Qt   = (f16*)alloc((size_t)NNN * DD * 2);
  f16* Kt   = (f16*)alloc((size_t)NNN * DD * 2);
  f16* Vb   = (f16*)alloc((size_t)CC * NNN * 2);
  f16* att  = (f16*)alloc((size_t)NNN * NNN * 2);  // per-batch, reused
  float* avg  = (float*)alloc((size_t)BBATCH * CC * 4);
  float* mxv  = (float*)alloc((size_t)BBATCH * CC * 4);
  float* gate = (float*)alloc((size_t)BBATCH * CC * 4);

  // weights -> f16 (once)
  cvt_f16<<<(DD * CC + 255) / 256, 256, 0, stream>>>(Wq, Wqb, DD * CC);
  cvt_f16<<<(DD * CC + 255) / 256, 256, 0, stream>>>(Wk, Wkb, DD * CC);
  cvt_f16<<<(CC * CC + 255) / 256, 256, 0, stream>>>(Wv, Wvb, CC * CC);

  const dim3 blk(256);
  const dim3 gT(NNN / 32, CC / 32);          // transpose grid
  const dim3 gQK(DD / BN, NNN / BM);         // (1, 32)
  const dim3 gV(NNN / BN, CC / BM);          // (32, 8)
  const dim3 gAtt(NNN / BN, NNN / BM);       // (32, 32)
  const dim3 gOut(NNN / BN, CC / BM);        // (32, 8)

  for (int b = 0; b < BBATCH; ++b) {
    const float* xb  = x  + (size_t)b * CC * NNN;
    const float* x1b = x1 + (size_t)b * CC * NNN;
    float* outb = out + (size_t)b * CC * NNN;

    transpose_cvt<<<gT, blk, 0, stream>>>(xb,  xTb,  CC, NNN);
    transpose_cvt<<<gT, blk, 0, stream>>>(x1b, x1Tb, CC, NNN);

    // Qt[n,d] = xT * Wq^T + bq ; Kt likewise (col bias)
    gemm_bt<2><<<gQK, blk, 0, stream>>>(xTb, Wqb, Qt, bq, NNN, DD, CC);
    gemm_bt<2><<<gQK, blk, 0, stream>>>(xTb, Wkb, Kt, bk, NNN, DD, CC);
    // V[c,m] = Wv * x1T^T + bv (row bias)
    gemm_bt<1><<<gV, blk, 0, stream>>>(Wvb, x1Tb, Vb, bv, CC, NNN, CC);
    // att[n,m] = sigmoid(Qt * Kt^T)
    gemm_bt<3><<<gAtt, blk, 0, stream>>>(Qt, Kt, att, nullptr, NNN, NNN, DD);
    // out[c,n] = V * att^T  (f32 straight to d_out)
    gemm_bt<0><<<gOut, blk, 0, stream>>>(Vb, att, outb, nullptr, CC, NNN, NNN);

    rowreduce<<<CC, blk, 0, stream>>>(outb, avg + b * CC, mxv + b * CC, NNN);
    mlp_gate<<<1, blk, 0, stream>>>(avg + b * CC, mxv + b * CC, Wca1, Wca2, gate + b * CC);
    scale_out<<<CC * NNN / 4 / 256, blk, 0, stream>>>(outb, gate + b * CC);
  }
}

// Round 3
// 563.725 us; speedup vs baseline: 1.9176x; 1.9176x over previous
//
#include <hip/hip_runtime.h>
#include <hip/hip_fp16.h>
#include <cstdint>

typedef _Float16 f16;
typedef __attribute__((ext_vector_type(8))) _Float16 half8;
typedef __attribute__((ext_vector_type(4))) float floatx4;

#define CC 1024
#define DD 128
#define RRR 64
#define BBATCH 4
#define NNN 4096   // H*W

// ---------------- GEMM: C[M,N] = A[M,K] * B[N,K]^T  (f16 in, f32 acc) ----------------
// LDS layout is XOR-swizzled on 16B granules: LDS[row][g] = G[row][g ^ (row&7)].
// global_load_lds forces LDS dest = base + lane*16, so the swizzle is applied by
// permuting the GLOBAL source granule per lane (same 128B line -> coalescing kept).
#define BM 128
#define BN 128
#define BK 64

__device__ __forceinline__ void gl_lds16(const void* g, void* l) {
  __builtin_amdgcn_global_load_lds(
      (__attribute__((address_space(1))) void*)(uintptr_t)g,
      (__attribute__((address_space(3))) void*)l, 16, 0, 0);
}

// EPI: 0 = f32 out, no bias | 1 = f16 out + row bias | 2 = f16 out + col bias | 3 = f16 sigmoid
template<int EPI>
__global__ __launch_bounds__(256)
void gemm_bt(const f16* __restrict__ A, const f16* __restrict__ Bp, void* __restrict__ Cout,
             const float* __restrict__ bias, int M, int N, int K,
             int lda, int ldb, int ldc, size_t sA, size_t sB, size_t sC)
{
  __shared__ __align__(16) f16 As[BM * BK];
  __shared__ __align__(16) f16 Bs[BN * BK];
  const int z = blockIdx.z;
  A  += (size_t)z * sA;
  Bp += (size_t)z * sB;

  const int tid  = threadIdx.x;
  const int lane = tid & 63;
  const int wave = tid >> 6;
  const int m0 = blockIdx.y * BM;
  const int n0 = blockIdx.x * BN;
  const int wm = (wave >> 1) * 64;
  const int wn = (wave & 1) * 64;

  floatx4 acc[4][4];
#pragma unroll
  for (int i = 0; i < 4; ++i)
#pragma unroll
    for (int j = 0; j < 4; ++j)
      acc[i][j] = (floatx4){0.f, 0.f, 0.f, 0.f};

  const int srow = lane >> 3;                 // 0..7 row within 8-row chunk
  const int sgr  = ((lane & 7) ^ srow) * 8;   // swizzled SOURCE granule (elems)
  const int sdst = (lane & 7) * 8;            // LDS slot (must stay lane-linear)
  const f16* aB = A  + (size_t)m0 * lda;
  const f16* bB = Bp + (size_t)n0 * ldb;

  const int quad = lane >> 4;                 // 0..3
  const int r16  = lane & 15;
  const int rs   = r16 & 7;                   // row&7 for swizzle readback

  for (int k0 = 0; k0 < K; k0 += BK) {
#pragma unroll
    for (int r = 0; r < 4; ++r) {
      const int row = (r * 4 + wave) * 8 + srow;
      gl_lds16(aB + (size_t)row * lda + k0 + sgr, As + row * BK + sdst);
      gl_lds16(bB + (size_t)row * ldb + k0 + sgr, Bs + row * BK + sdst);
    }
    __syncthreads();

#pragma unroll
    for (int kk = 0; kk < BK; kk += 32) {
      const int kg = kk >> 3;                 // granule base: 0 or 4
      half8 af[4], bfr[4];
#pragma unroll
      for (int i = 0; i < 4; ++i)
        af[i] = *(const half8*)(As + (wm + i * 16 + r16) * BK + (((quad + kg) ^ rs) * 8));
#pragma unroll
      for (int j = 0; j < 4; ++j)
        bfr[j] = *(const half8*)(Bs + (wn + j * 16 + r16) * BK + (((quad + kg) ^ rs) * 8));
#pragma unroll
      for (int i = 0; i < 4; ++i)
#pragma unroll
        for (int j = 0; j < 4; ++j)
          acc[i][j] = __builtin_amdgcn_mfma_f32_16x16x32_f16(af[i], bfr[j], acc[i][j], 0, 0, 0);
    }
    __syncthreads();
  }

  // epilogue: C/D layout col=lane&15, row=quad*4+reg
  float* Cf = (EPI == 0) ? ((float*)Cout + (size_t)z * sC) : nullptr;
  f16*   Ch = (EPI != 0) ? ((f16*)Cout   + (size_t)z * sC) : nullptr;
#pragma unroll
  for (int i = 0; i < 4; ++i) {
#pragma unroll
    for (int r = 0; r < 4; ++r) {
      const int row = m0 + wm + i * 16 + quad * 4 + r;
#pragma unroll
      for (int j = 0; j < 4; ++j) {
        const int col = n0 + wn + j * 16 + r16;
        float v = acc[i][j][r];
        if constexpr (EPI == 0) {
          Cf[(size_t)row * ldc + col] = v;
        } else if constexpr (EPI == 1) {
          Ch[(size_t)row * ldc + col] = (f16)(v + bias[row]);
        } else if constexpr (EPI == 2) {
          Ch[(size_t)row * ldc + col] = (f16)(v + bias[col]);
        } else {
          Ch[(size_t)row * ldc + col] = (f16)(1.0f / (1.0f + __expf(-v)));
        }
      }
    }
  }
}

// ---------------- transpose + f32->f16: in[rows][cols] f32 -> out[cols][rows] f16 ----------------
__global__ __launch_bounds__(256)
void transpose_cvt(const float* __restrict__ in, f16* __restrict__ out, int rows, int cols)
{
  const size_t zo = (size_t)blockIdx.z * rows * cols;
  in += zo; out += zo;
  __shared__ float tile[32][33];
  const int c0 = blockIdx.y * 32;
  const int n0 = blockIdx.x * 32;
  const int tx = threadIdx.x & 31;
  const int ty = threadIdx.x >> 5;   // 0..7
#pragma unroll
  for (int r = 0; r < 32; r += 8)
    tile[ty + r][tx] = in[(size_t)(c0 + ty + r) * cols + n0 + tx];
  __syncthreads();
#pragma unroll
  for (int r = 0; r < 32; r += 8)
    out[(size_t)(n0 + ty + r) * rows + c0 + tx] = (f16)tile[tx][ty + r];
}

// ---------------- f32 -> f16 elementwise ----------------
__global__ __launch_bounds__(256)
void cvt_f16(const float* __restrict__ in, f16* __restrict__ out, int n)
{
  int i = blockIdx.x * 256 + threadIdx.x;
  if (i < n) out[i] = (f16)in[i];
}

// ---------------- concat two 128-float biases ----------------
__global__ void concat_bias(const float* __restrict__ a, const float* __restrict__ b,
                            float* __restrict__ o)
{
  int t = threadIdx.x;
  o[t] = (t < 128) ? a[t] : b[t - 128];
}

// ---------------- per-row mean + max over ncols; grid (CC, nbatch) ----------------
__global__ __launch_bounds__(256)
void rowreduce(const float* __restrict__ X, float* __restrict__ avg, float* __restrict__ mx, int ncols)
{
  const size_t ridx = (size_t)blockIdx.y * gridDim.x + blockIdx.x;
  const float4* p = (const float4*)(X + ridx * ncols);
  float s = 0.f, m = -3.402823466e38f;
  for (int i = threadIdx.x; i < ncols / 4; i += 256) {
    float4 v = p[i];
    s += v.x + v.y + v.z + v.w;
    m = fmaxf(m, fmaxf(fmaxf(v.x, v.y), fmaxf(v.z, v.w)));
  }
#pragma unroll
  for (int o = 32; o > 0; o >>= 1) {
    s += __shfl_down(s, o);
    m = fmaxf(m, __shfl_down(m, o));
  }
  __shared__ float ss[4], sm[4];
  if ((threadIdx.x & 63) == 0) { ss[threadIdx.x >> 6] = s; sm[threadIdx.x >> 6] = m; }
  __syncthreads();
  if (threadIdx.x == 0) {
    s = ss[0] + ss[1] + ss[2] + ss[3];
    m = fmaxf(fmaxf(sm[0], sm[1]), fmaxf(sm[2], sm[3]));
    avg[ridx] = s / (float)ncols;
    mx[ridx] = m;
  }
}

// ---------------- CBAM MLP gate; grid (nbatch) ----------------
__global__ __launch_bounds__(256)
void mlp_gate(const float* __restrict__ avg, const float* __restrict__ mxv,
              const float* __restrict__ W1 /*[64][1024]*/, const float* __restrict__ W2 /*[1024][64]*/,
              float* __restrict__ gate)
{
  const int z = blockIdx.x;
  avg += (size_t)z * CC; mxv += (size_t)z * CC; gate += (size_t)z * CC;
  const int t = threadIdx.x;
  const int r = t & 63;
  const int part = t >> 6;           // 0..3, each covers 256 c
  __shared__ float pa[4][64], pm[4][64], h[RRR];
  {
    const float* w = W1 + (size_t)r * CC + part * 256;
    const float* av = avg + part * 256;
    const float* mv = mxv + part * 256;
    float sa = 0.f, sm = 0.f;
    for (int c = 0; c < 256; ++c) { float wv = w[c]; sa += wv * av[c]; sm += wv * mv[c]; }
    pa[part][r] = sa; pm[part][r] = sm;
  }
  __syncthreads();
  if (t < RRR) {
    float A_ = pa[0][t] + pa[1][t] + pa[2][t] + pa[3][t];
    float M_ = pm[0][t] + pm[1][t] + pm[2][t] + pm[3][t];
    h[t] = fmaxf(A_, 0.f) + fmaxf(M_, 0.f);
  }
  __syncthreads();
  for (int c = t; c < CC; c += 256) {
    float s = 0.f;
    for (int rr = 0; rr < RRR; ++rr) s += W2[(size_t)c * RRR + rr] * h[rr];
    gate[c] = 1.0f / (1.0f + __expf(-s));
  }
}

// ---------------- apply gate in place; grid (CC*NNN/1024, nbatch) ----------------
__global__ __launch_bounds__(256)
void scale_out(float* __restrict__ out, const float* __restrict__ gate)
{
  out  += (size_t)blockIdx.y * CC * NNN;
  gate += (size_t)blockIdx.y * CC;
  size_t i = (size_t)blockIdx.x * 256 + threadIdx.x;   // over C*N/4
  float4* p = (float4*)out;
  const float g = gate[(i * 4) >> 12];                 // N = 4096 = 2^12
  float4 v = p[i];
  v.x *= g; v.y *= g; v.z *= g; v.w *= g;
  p[i] = v;
}

// ---------------- launch ----------------
extern "C" void kernel_launch(void* const* d_in, const int* in_sizes, int n_in,
                              void* d_out, int out_size, void* d_ws, size_t ws_size,
                              hipStream_t stream)
{
  const float* x    = (const float*)d_in[0];
  const float* x1   = (const float*)d_in[1];
  const float* Wq   = (const float*)d_in[2];
  const float* bq   = (const float*)d_in[3];
  const float* Wk   = (const float*)d_in[4];
  const float* bk   = (const float*)d_in[5];
  const float* Wv   = (const float*)d_in[6];
  const float* bv   = (const float*)d_in[7];
  const float* Wca1 = (const float*)d_in[8];
  const float* Wca2 = (const float*)d_in[9];
  float* out = (float*)d_out;

  char* ws = (char*)d_ws;
  size_t off = 0;
  auto alloc = [&](size_t bytes) { void* p = ws + off; off += (bytes + 255) & ~255ULL; return p; };

  // small fixed buffers
  f16* WQKb = (f16*)alloc((size_t)2 * DD * CC * 2);     // [256][1024] stacked Wq;Wk
  f16* Wvb  = (f16*)alloc((size_t)CC * CC * 2);
  float* bqk  = (float*)alloc(256 * 4);
  float* avg  = (float*)alloc((size_t)BBATCH * CC * 4);
  float* mxv  = (float*)alloc((size_t)BBATCH * CC * 4);
  float* gate = (float*)alloc((size_t)BBATCH * CC * 4);

  const size_t attB  = (size_t)NNN * NNN * 2;           // 32 MiB per batch
  const size_t xTB   = (size_t)BBATCH * NNN * CC * 2;   // 32 MiB
  const size_t qkB   = (size_t)BBATCH * NNN * 2 * DD * 2; // 8 MiB
  const size_t vBB   = (size_t)BBATCH * CC * NNN * 2;   // 32 MiB
  const size_t fixedEnd = off;

  int g = 0;
  for (int cand = BBATCH; cand >= 1; cand >>= 1) {
    size_t need = fixedEnd + 2 * xTB + qkB + vBB + (size_t)cand * attB + (1 << 20);
    if (need <= ws_size) { g = cand; break; }
  }

  const dim3 blk(256);
  // weights -> f16 (shared by both modes)
  cvt_f16<<<(DD * CC + 255) / 256, blk, 0, stream>>>(Wq, WQKb, DD * CC);
  cvt_f16<<<(DD * CC + 255) / 256, blk, 0, stream>>>(Wk, WQKb + (size_t)DD * CC, DD * CC);
  cvt_f16<<<(CC * CC + 255) / 256, blk, 0, stream>>>(Wv, Wvb, CC * CC);
  concat_bias<<<1, blk, 0, stream>>>(bq, bk, bqk);

  if (g > 0) {
    // -------- fully batched mode --------
    f16* xTb  = (f16*)alloc(xTB);
    f16* x1Tb = (f16*)alloc(xTB);
    f16* QKt  = (f16*)alloc(qkB);     // [b][n][256] : cols 0..127 = Q, 128..255 = K
    f16* Vb   = (f16*)alloc(vBB);     // [b][c][m]
    f16* att  = (f16*)alloc((size_t)g * attB);

    transpose_cvt<<<dim3(NNN / 32, CC / 32, BBATCH), blk, 0, stream>>>(x,  xTb,  CC, NNN);
    transpose_cvt<<<dim3(NNN / 32, CC / 32, BBATCH), blk, 0, stream>>>(x1, x1Tb, CC, NNN);

    // QK: [n,256] = xT[n,:] . WQK^T + bqk
    gemm_bt<2><<<dim3(2 * DD / BN, NNN / BM, BBATCH), blk, 0, stream>>>(
        xTb, WQKb, QKt, bqk, NNN, 2 * DD, CC,
        CC, CC, 2 * DD, (size_t)NNN * CC, 0, (size_t)NNN * 2 * DD);
    // V: [c,m] = Wv . x1T^T + bv
    gemm_bt<1><<<dim3(NNN / BN, CC / BM, BBATCH), blk, 0, stream>>>(
        Wvb, x1Tb, Vb, bv, CC, NNN, CC,
        CC, CC, NNN, 0, (size_t)NNN * CC, (size_t)CC * NNN);

    for (int b0 = 0; b0 < BBATCH; b0 += g) {
      const int gc = (b0 + g <= BBATCH) ? g : (BBATCH - b0);
      const size_t sQK = (size_t)NNN * 2 * DD;
      // att[n,m] = sigmoid(Q[n,:] . K[m,:]^T)
      gemm_bt<3><<<dim3(NNN / BN, NNN / BM, gc), blk, 0, stream>>>(
          QKt + (size_t)b0 * sQK, QKt + (size_t)b0 * sQK + DD, att, nullptr,
          NNN, NNN, DD, 2 * DD, 2 * DD, NNN, sQK, sQK, (size_t)NNN * NNN);
      // out[c,n] = V[c,:] . att[n,:]^T
      gemm_bt<0><<<dim3(NNN / BN, CC / BM, gc), blk, 0, stream>>>(
          Vb + (size_t)b0 * CC * NNN, att, out + (size_t)b0 * CC * NNN, nullptr,
          CC, NNN, NNN, NNN, NNN, NNN,
          (size_t)CC * NNN, (size_t)NNN * NNN, (size_t)CC * NNN);
    }

    rowreduce<<<dim3(CC, BBATCH), blk, 0, stream>>>(out, avg, mxv, NNN);
    mlp_gate<<<BBATCH, blk, 0, stream>>>(avg, mxv, Wca1, Wca2, gate);
    scale_out<<<dim3(CC * NNN / 4 / 256, BBATCH), blk, 0, stream>>>(out, gate);
  } else {
    // -------- legacy per-batch mode (ws-constrained; known to fit ~61 MiB) --------
    f16* xTb  = (f16*)alloc((size_t)NNN * CC * 2);
    f16* x1Tb = (f16*)alloc((size_t)NNN * CC * 2);
    f16* QKt  = (f16*)alloc((size_t)NNN * 2 * DD * 2);
    f16* Vb   = (f16*)alloc((size_t)CC * NNN * 2);
    f16* att  = (f16*)alloc(attB);

    for (int b = 0; b < BBATCH; ++b) {
      const float* xb  = x  + (size_t)b * CC * NNN;
      const float* x1b = x1 + (size_t)b * CC * NNN;
      float* outb = out + (size_t)b * CC * NNN;

      transpose_cvt<<<dim3(NNN / 32, CC / 32, 1), blk, 0, stream>>>(xb,  xTb,  CC, NNN);
      transpose_cvt<<<dim3(NNN / 32, CC / 32, 1), blk, 0, stream>>>(x1b, x1Tb, CC, NNN);

      gemm_bt<2><<<dim3(2 * DD / BN, NNN / BM, 1), blk, 0, stream>>>(
          xTb, WQKb, QKt, bqk, NNN, 2 * DD, CC, CC, CC, 2 * DD, 0, 0, 0);
      gemm_bt<1><<<dim3(NNN / BN, CC / BM, 1), blk, 0, stream>>>(
          Wvb, x1Tb, Vb, bv, CC, NNN, CC, CC, CC, NNN, 0, 0, 0);
      gemm_bt<3><<<dim3(NNN / BN, NNN / BM, 1), blk, 0, stream>>>(
          QKt, QKt + DD, att, nullptr, NNN, NNN, DD, 2 * DD, 2 * DD, NNN, 0, 0, 0);
      gemm_bt<0><<<dim3(NNN / BN, CC / BM, 1), blk, 0, stream>>>(
          Vb, att, outb, nullptr, CC, NNN, NNN, NNN, NNN, NNN, 0, 0, 0);

      rowreduce<<<dim3(CC, 1), blk, 0, stream>>>(outb, avg + (size_t)b * CC, mxv + (size_t)b * CC, NNN);
      mlp_gate<<<1, blk, 0, stream>>>(avg + (size_t)b * CC, mxv + (size_t)b * CC, Wca1, Wca2, gate + (size_t)b * CC);
      scale_out<<<dim3(CC * NNN / 4 / 256, 1), blk, 0, stream>>>(outb, gate + (size_t)b * CC);
    }
  }
}

// Round 4
// 543.556 us; speedup vs baseline: 1.9887x; 1.0371x over previous
//
#include <hip/hip_runtime.h>
#include <hip/hip_fp16.h>
#include <cstdint>

typedef _Float16 f16;
typedef __attribute__((ext_vector_type(8))) _Float16 half8;
typedef __attribute__((ext_vector_type(4))) float floatx4;

#define CC 1024
#define DD 128
#define RRR 64
#define BBATCH 4
#define NNN 4096   // H*W

#define BM 128
#define BN 128

__device__ __forceinline__ void gl_lds16(const void* g, void* l) {
  __builtin_amdgcn_global_load_lds(
      (__attribute__((address_space(1))) void*)(uintptr_t)g,
      (__attribute__((address_space(3))) void*)l, 16, 0, 0);
}

// ---------------- GEMM: C[M,N] = A[M,K] * B[N,K]^T  (f16 in, f32 acc) ----------------
// LDS tiles XOR-swizzled on 16B granules: LDS[row][g] = G[row][g ^ (row&7)]; the
// swizzle is applied on the GLOBAL source granule (dest must stay lane-linear for
// global_load_lds), permutation stays within one 128B line -> coalescing kept.
// EPI: 0 = f32 out direct | 1 = f16 + row bias | 2 = f16 + col bias | 3 = f16 sigmoid
// EPI 1-3 repack the C tile through LDS for 16B coalesced stores.
template<int EPI, int BKT>
__global__ __launch_bounds__(256)
void gemm_bt(const f16* __restrict__ A, const f16* __restrict__ Bp, void* __restrict__ Cout,
             const float* __restrict__ bias, int M, int N, int K,
             int lda, int ldb, int ldc, size_t sA, size_t sB, size_t sC)
{
  constexpr int GPR = BKT / 8;                 // 16B granules per row
  constexpr int LOG2GPR = (BKT == 64) ? 3 : 4;
  constexpr int GIT = (BM * GPR) / 256;        // staging iters per operand
  __shared__ __align__(16) f16 S[2 * BM * BKT];
  f16* As = S;
  f16* Bs = S + BM * BKT;

  const int z = blockIdx.z;
  const int tid  = threadIdx.x;
  const int lane = tid & 63;
  const int wave = tid >> 6;
  const int m0 = blockIdx.y * BM;
  const int n0 = blockIdx.x * BN;
  const int wm = (wave >> 1) * 64;
  const int wn = (wave & 1) * 64;
  const int quad = lane >> 4;
  const int r16  = lane & 15;
  const int rs   = r16 & 7;

  const f16* Ab = A  + (size_t)z * sA + (size_t)m0 * lda;
  const f16* Bb = Bp + (size_t)z * sB + (size_t)n0 * ldb;

  floatx4 acc[4][4];
#pragma unroll
  for (int i = 0; i < 4; ++i)
#pragma unroll
    for (int j = 0; j < 4; ++j)
      acc[i][j] = (floatx4){0.f, 0.f, 0.f, 0.f};

  int srow[GIT], ssrc[GIT];
#pragma unroll
  for (int r = 0; r < GIT; ++r) {
    const int gi = r * 256 + tid;
    const int row = gi >> LOG2GPR;
    const int gc  = gi & (GPR - 1);
    srow[r] = row;
    ssrc[r] = ((gc ^ (row & 7)) << 3);
  }

  for (int k0 = 0; k0 < K; k0 += BKT) {
#pragma unroll
    for (int r = 0; r < GIT; ++r) {
      gl_lds16(Ab + (size_t)srow[r] * lda + k0 + ssrc[r], As + (size_t)(r * 256 + tid) * 8);
      gl_lds16(Bb + (size_t)srow[r] * ldb + k0 + ssrc[r], Bs + (size_t)(r * 256 + tid) * 8);
    }
    __syncthreads();

#pragma unroll
    for (int kk = 0; kk < BKT; kk += 32) {
      const int kg = kk >> 3;
      half8 af[4], bfr[4];
#pragma unroll
      for (int i = 0; i < 4; ++i)
        af[i] = *(const half8*)(As + (wm + i * 16 + r16) * BKT + (((quad + kg) ^ rs) << 3));
#pragma unroll
      for (int j = 0; j < 4; ++j)
        bfr[j] = *(const half8*)(Bs + (wn + j * 16 + r16) * BKT + (((quad + kg) ^ rs) << 3));
#pragma unroll
      for (int i = 0; i < 4; ++i)
#pragma unroll
        for (int j = 0; j < 4; ++j)
          acc[i][j] = __builtin_amdgcn_mfma_f32_16x16x32_f16(af[i], bfr[j], acc[i][j], 0, 0, 0);
    }
    __syncthreads();
  }

  // epilogue: C/D layout col=lane&15, row=quad*4+reg
  if constexpr (EPI == 0) {
    float* Cf = (float*)Cout + (size_t)z * sC;
#pragma unroll
    for (int i = 0; i < 4; ++i)
#pragma unroll
      for (int r = 0; r < 4; ++r) {
        const int row = m0 + wm + i * 16 + quad * 4 + r;
#pragma unroll
        for (int j = 0; j < 4; ++j)
          Cf[(size_t)row * ldc + n0 + wn + j * 16 + r16] = acc[i][j][r];
      }
  } else {
    f16* Ch = (f16*)Cout + (size_t)z * sC;
    f16* Ct = S;   // 128x128 f16 = 32 KB, granule-swizzled per row
#pragma unroll
    for (int i = 0; i < 4; ++i)
#pragma unroll
      for (int r = 0; r < 4; ++r) {
        const int rl = wm + i * 16 + quad * 4 + r;
#pragma unroll
        for (int j = 0; j < 4; ++j) {
          const int cl = wn + j * 16 + r16;
          const float v = acc[i][j][r];
          f16 h;
          if constexpr (EPI == 1)      h = (f16)(v + bias[m0 + rl]);
          else if constexpr (EPI == 2) h = (f16)(v + bias[n0 + cl]);
          else                         h = (f16)(1.0f / (1.0f + __expf(-v)));
          Ct[rl * BN + ((((cl >> 3) ^ (rl & 7)) << 3) | (cl & 7))] = h;
        }
      }
    __syncthreads();
#pragma unroll
    for (int p = 0; p < 8; ++p) {
      const int idx = p * 256 + tid;
      const int rl = idx >> 4;
      const int g  = idx & 15;
      half8 vv = *(const half8*)(Ct + rl * BN + (((g ^ (rl & 7))) << 3));
      *(half8*)(Ch + (size_t)(m0 + rl) * ldc + n0 + g * 8) = vv;
    }
  }
}

// ---------------- weights f32->f16 + bias concat, one dispatch ----------------
__global__ __launch_bounds__(256)
void prep(const float* __restrict__ Wq, const float* __restrict__ Wk, const float* __restrict__ Wv,
          const float* __restrict__ bq, const float* __restrict__ bk,
          f16* __restrict__ WQKb, f16* __restrict__ Wvb, float* __restrict__ bqk)
{
  const int NV = CC * CC;
  const int NQ = DD * CC;
  int i = blockIdx.x * 256 + threadIdx.x;
  if (i < NV)                    Wvb[i] = (f16)Wv[i];
  else if (i < NV + NQ)          WQKb[i - NV] = (f16)Wq[i - NV];
  else if (i < NV + 2 * NQ)      WQKb[i - NV] = (f16)Wk[i - NV - NQ];
  else if (i < NV + 2 * NQ + 2 * DD) {
    int t = i - NV - 2 * NQ;
    bqk[t] = (t < DD) ? bq[t] : bk[t - DD];
  }
}

// ---------------- transpose + f32->f16 for x and x1 in one dispatch ----------------
// z in [0, 2*nb): z < nb -> x[batch z] -> ox ; else x1[batch z-nb] -> ox1
__global__ __launch_bounds__(256)
void transpose_cvt(const float* __restrict__ x, const float* __restrict__ x1,
                   f16* __restrict__ ox, f16* __restrict__ ox1, int nb)
{
  const int zz = blockIdx.z;
  const int b  = (zz < nb) ? zz : zz - nb;
  const float* in = ((zz < nb) ? x : x1) + (size_t)b * CC * NNN;
  f16* out = ((zz < nb) ? ox : ox1) + (size_t)b * CC * NNN;
  __shared__ float tile[32][33];
  const int c0 = blockIdx.y * 32;
  const int n0 = blockIdx.x * 32;
  const int tx = threadIdx.x & 31;
  const int ty = threadIdx.x >> 5;
#pragma unroll
  for (int r = 0; r < 32; r += 8)
    tile[ty + r][tx] = in[(size_t)(c0 + ty + r) * NNN + n0 + tx];
  __syncthreads();
#pragma unroll
  for (int r = 0; r < 32; r += 8)
    out[(size_t)(n0 + ty + r) * CC + c0 + tx] = (f16)tile[tx][ty + r];
}

// ---------------- per-row mean + max over ncols; grid (CC, nbatch) ----------------
__global__ __launch_bounds__(256)
void rowreduce(const float* __restrict__ X, float* __restrict__ avg, float* __restrict__ mx, int ncols)
{
  const size_t ridx = (size_t)blockIdx.y * gridDim.x + blockIdx.x;
  const float4* p = (const float4*)(X + ridx * ncols);
  float s = 0.f, m = -3.402823466e38f;
  for (int i = threadIdx.x; i < ncols / 4; i += 256) {
    float4 v = p[i];
    s += v.x + v.y + v.z + v.w;
    m = fmaxf(m, fmaxf(fmaxf(v.x, v.y), fmaxf(v.z, v.w)));
  }
#pragma unroll
  for (int o = 32; o > 0; o >>= 1) {
    s += __shfl_down(s, o);
    m = fmaxf(m, __shfl_down(m, o));
  }
  __shared__ float ss[4], sm[4];
  if ((threadIdx.x & 63) == 0) { ss[threadIdx.x >> 6] = s; sm[threadIdx.x >> 6] = m; }
  __syncthreads();
  if (threadIdx.x == 0) {
    s = ss[0] + ss[1] + ss[2] + ss[3];
    m = fmaxf(fmaxf(sm[0], sm[1]), fmaxf(sm[2], sm[3]));
    avg[ridx] = s / (float)ncols;
    mx[ridx] = m;
  }
}

// ---------------- CBAM MLP gate; grid (nbatch) ----------------
__global__ __launch_bounds__(256)
void mlp_gate(const float* __restrict__ avg, const float* __restrict__ mxv,
              const float* __restrict__ W1, const float* __restrict__ W2,
              float* __restrict__ gate)
{
  const int z = blockIdx.x;
  avg += (size_t)z * CC; mxv += (size_t)z * CC; gate += (size_t)z * CC;
  const int t = threadIdx.x;
  const int r = t & 63;
  const int part = t >> 6;
  __shared__ float pa[4][64], pm[4][64], h[RRR];
  {
    const float* w = W1 + (size_t)r * CC + part * 256;
    const float* av = avg + part * 256;
    const float* mv = mxv + part * 256;
    float sa = 0.f, sm = 0.f;
    for (int c = 0; c < 256; ++c) { float wv = w[c]; sa += wv * av[c]; sm += wv * mv[c]; }
    pa[part][r] = sa; pm[part][r] = sm;
  }
  __syncthreads();
  if (t < RRR) {
    float A_ = pa[0][t] + pa[1][t] + pa[2][t] + pa[3][t];
    float M_ = pm[0][t] + pm[1][t] + pm[2][t] + pm[3][t];
    h[t] = fmaxf(A_, 0.f) + fmaxf(M_, 0.f);
  }
  __syncthreads();
  for (int c = t; c < CC; c += 256) {
    float s = 0.f;
    for (int rr = 0; rr < RRR; ++rr) s += W2[(size_t)c * RRR + rr] * h[rr];
    gate[c] = 1.0f / (1.0f + __expf(-s));
  }
}

// ---------------- apply gate in place; grid (CC*NNN/1024, nbatch) ----------------
__global__ __launch_bounds__(256)
void scale_out(float* __restrict__ out, const float* __restrict__ gate)
{
  out  += (size_t)blockIdx.y * CC * NNN;
  gate += (size_t)blockIdx.y * CC;
  size_t i = (size_t)blockIdx.x * 256 + threadIdx.x;
  float4* p = (float4*)out;
  const float g = gate[(i * 4) >> 12];
  float4 v = p[i];
  v.x *= g; v.y *= g; v.z *= g; v.w *= g;
  p[i] = v;
}

// ---------------- launch ----------------
extern "C" void kernel_launch(void* const* d_in, const int* in_sizes, int n_in,
                              void* d_out, int out_size, void* d_ws, size_t ws_size,
                              hipStream_t stream)
{
  const float* x    = (const float*)d_in[0];
  const float* x1   = (const float*)d_in[1];
  const float* Wq   = (const float*)d_in[2];
  const float* bq   = (const float*)d_in[3];
  const float* Wk   = (const float*)d_in[4];
  const float* bk   = (const float*)d_in[5];
  const float* Wv   = (const float*)d_in[6];
  const float* bv   = (const float*)d_in[7];
  const float* Wca1 = (const float*)d_in[8];
  const float* Wca2 = (const float*)d_in[9];
  float* out = (float*)d_out;

  char* ws = (char*)d_ws;
  size_t off = 0;
  auto alloc = [&](size_t bytes) { void* p = ws + off; off += (bytes + 255) & ~255ULL; return p; };

  f16* WQKb = (f16*)alloc((size_t)2 * DD * CC * 2);
  f16* Wvb  = (f16*)alloc((size_t)CC * CC * 2);
  float* bqk  = (float*)alloc(256 * 4);
  float* avg  = (float*)alloc((size_t)BBATCH * CC * 4);
  float* mxv  = (float*)alloc((size_t)BBATCH * CC * 4);
  float* gate = (float*)alloc((size_t)BBATCH * CC * 4);

  const size_t attB = (size_t)NNN * NNN * 2;
  const size_t xTB  = (size_t)BBATCH * NNN * CC * 2;
  const size_t qkB  = (size_t)BBATCH * NNN * 2 * DD * 2;
  const size_t vBB  = (size_t)BBATCH * CC * NNN * 2;
  const size_t fixedEnd = off;

  int g = 0;
  for (int cand = BBATCH; cand >= 1; cand >>= 1) {
    size_t need = fixedEnd + 2 * xTB + qkB + vBB + (size_t)cand * attB + (1 << 20);
    if (need <= ws_size) { g = cand; break; }
  }

  const dim3 blk(256);
  const int prepN = CC * CC + 2 * DD * CC + 2 * DD;
  prep<<<(prepN + 255) / 256, blk, 0, stream>>>(Wq, Wk, Wv, bq, bk, WQKb, Wvb, bqk);

  if (g > 0) {
    f16* xTb  = (f16*)alloc(xTB);
    f16* x1Tb = (f16*)alloc(xTB);
    f16* QKt  = (f16*)alloc(qkB);     // [b][n][256] : 0..127 = Q, 128..255 = K
    f16* Vb   = (f16*)alloc(vBB);     // [b][c][m]
    f16* att  = (f16*)alloc((size_t)g * attB);

    transpose_cvt<<<dim3(NNN / 32, CC / 32, 2 * BBATCH), blk, 0, stream>>>(x, x1, xTb, x1Tb, BBATCH);

    gemm_bt<2, 64><<<dim3(2 * DD / BN, NNN / BM, BBATCH), blk, 0, stream>>>(
        xTb, WQKb, QKt, bqk, NNN, 2 * DD, CC,
        CC, CC, 2 * DD, (size_t)NNN * CC, 0, (size_t)NNN * 2 * DD);
    gemm_bt<1, 64><<<dim3(NNN / BN, CC / BM, BBATCH), blk, 0, stream>>>(
        Wvb, x1Tb, Vb, bv, CC, NNN, CC,
        CC, CC, NNN, 0, (size_t)NNN * CC, (size_t)CC * NNN);

    for (int b0 = 0; b0 < BBATCH; b0 += g) {
      const int gc = (b0 + g <= BBATCH) ? g : (BBATCH - b0);
      const size_t sQK = (size_t)NNN * 2 * DD;
      gemm_bt<3, 128><<<dim3(NNN / BN, NNN / BM, gc), blk, 0, stream>>>(
          QKt + (size_t)b0 * sQK, QKt + (size_t)b0 * sQK + DD, att, nullptr,
          NNN, NNN, DD, 2 * DD, 2 * DD, NNN, sQK, sQK, (size_t)NNN * NNN);
      gemm_bt<0, 64><<<dim3(NNN / BN, CC / BM, gc), blk, 0, stream>>>(
          Vb + (size_t)b0 * CC * NNN, att, out + (size_t)b0 * CC * NNN, nullptr,
          CC, NNN, NNN, NNN, NNN, NNN,
          (size_t)CC * NNN, (size_t)NNN * NNN, (size_t)CC * NNN);
    }

    rowreduce<<<dim3(CC, BBATCH), blk, 0, stream>>>(out, avg, mxv, NNN);
    mlp_gate<<<BBATCH, blk, 0, stream>>>(avg, mxv, Wca1, Wca2, gate);
    scale_out<<<dim3(CC * NNN / 4 / 256, BBATCH), blk, 0, stream>>>(out, gate);
  } else {
    // legacy per-batch mode (ws-constrained fallback)
    f16* xTb  = (f16*)alloc((size_t)NNN * CC * 2);
    f16* x1Tb = (f16*)alloc((size_t)NNN * CC * 2);
    f16* QKt  = (f16*)alloc((size_t)NNN * 2 * DD * 2);
    f16* Vb   = (f16*)alloc((size_t)CC * NNN * 2);
    f16* att  = (f16*)alloc(attB);

    for (int b = 0; b < BBATCH; ++b) {
      const float* xb  = x  + (size_t)b * CC * NNN;
      const float* x1b = x1 + (size_t)b * CC * NNN;
      float* outb = out + (size_t)b * CC * NNN;

      transpose_cvt<<<dim3(NNN / 32, CC / 32, 2), blk, 0, stream>>>(xb, x1b, xTb, x1Tb, 1);

      gemm_bt<2, 64><<<dim3(2 * DD / BN, NNN / BM, 1), blk, 0, stream>>>(
          xTb, WQKb, QKt, bqk, NNN, 2 * DD, CC, CC, CC, 2 * DD, 0, 0, 0);
      gemm_bt<1, 64><<<dim3(NNN / BN, CC / BM, 1), blk, 0, stream>>>(
          Wvb, x1Tb, Vb, bv, CC, NNN, CC, CC, CC, NNN, 0, 0, 0);
      gemm_bt<3, 128><<<dim3(NNN / BN, NNN / BM, 1), blk, 0, stream>>>(
          QKt, QKt + DD, att, nullptr, NNN, NNN, DD, 2 * DD, 2 * DD, NNN, 0, 0, 0);
      gemm_bt<0, 64><<<dim3(NNN / BN, CC / BM, 1), blk, 0, stream>>>(
          Vb, att, outb, nullptr, CC, NNN, NNN, NNN, NNN, NNN, 0, 0, 0);

      rowreduce<<<dim3(CC, 1), blk, 0, stream>>>(outb, avg + (size_t)b * CC, mxv + (size_t)b * CC, NNN);
      mlp_gate<<<1, blk, 0, stream>>>(avg + (size_t)b * CC, mxv + (size_t)b * CC, Wca1, Wca2, gate + (size_t)b * CC);
      scale_out<<<dim3(CC * NNN / 4 / 256, 1), blk, 0, stream>>>(outb, gate + (size_t)b * CC);
    }
  }
}

// Round 5
// 517.066 us; speedup vs baseline: 2.0906x; 1.0512x over previous
//
#include <hip/hip_runtime.h>
#include <hip/hip_fp16.h>
#include <cstdint>

typedef _Float16 f16;
typedef __attribute__((ext_vector_type(8))) _Float16 half8;
typedef __attribute__((ext_vector_type(16))) float floatx16;

#define CC 1024
#define DD 128
#define RRR 64
#define BBATCH 4
#define NNN 4096   // H*W

#define BM 128
#define BN 128
#define BK 64

__device__ __forceinline__ void gl_lds16(const void* g, void* l) {
  __builtin_amdgcn_global_load_lds(
      (__attribute__((address_space(1))) void*)(uintptr_t)g,
      (__attribute__((address_space(3))) void*)l, 16, 0, 0);
}

// ---------------- GEMM: C[M,N] = A[M,K] * B[N,K]^T  (f16 in, f32 acc, f16 out) ----------------
// mfma_f32_32x32x16_f16: A[m=lane&31][k=(lane>>5)*8+j], B likewise;
// C/D: col=lane&31, row=(reg&3)+8*(reg>>2)+4*(lane>>5)   [m74/m101 verified]
// LDS tiles XOR-swizzled on 16B granules: LDS[row][g] = G[row][g ^ (row&7)] (swizzle applied
// on the GLOBAL source granule; dest stays lane-linear for global_load_lds; same 128B line).
// EPI: 0 = plain | 1 = + row bias | 2 = + col bias | 3 = sigmoid. All f16 out via LDS repack.
template<int EPI>
__global__ __launch_bounds__(256)
void gemm_bt(const f16* __restrict__ A, const f16* __restrict__ Bp, f16* __restrict__ Cout,
             const float* __restrict__ bias, int N, int K,
             int lda, int ldb, int ldc, size_t sA, size_t sB, size_t sC)
{
  __shared__ __align__(16) f16 S[2 * BM * BK];      // 32 KiB
  f16* As = S;
  f16* Bs = S + BM * BK;

  const int z = blockIdx.z;
  const int tid  = threadIdx.x;
  const int lane = tid & 63;
  const int wave = tid >> 6;
  const int m0 = blockIdx.y * BM;
  const int n0 = blockIdx.x * BN;
  const int wm = (wave >> 1) * 64;
  const int wn = (wave & 1) * 64;
  const int l31 = lane & 31;
  const int hi  = lane >> 5;
  const int rs  = lane & 7;

  const f16* Ab = A  + (size_t)z * sA + (size_t)m0 * lda;
  const f16* Bb = Bp + (size_t)z * sB + (size_t)n0 * ldb;

  floatx16 acc[2][2];
#pragma unroll
  for (int i = 0; i < 2; ++i)
#pragma unroll
    for (int j = 0; j < 2; ++j)
#pragma unroll
      for (int r = 0; r < 16; ++r)
        acc[i][j][r] = 0.f;

  int srow[4], ssrc[4];
#pragma unroll
  for (int r = 0; r < 4; ++r) {
    const int gi = r * 256 + tid;
    const int row = gi >> 3;
    const int gc  = gi & 7;
    srow[r] = row;
    ssrc[r] = ((gc ^ (row & 7)) << 3);
  }

  for (int k0 = 0; k0 < K; k0 += BK) {
#pragma unroll
    for (int r = 0; r < 4; ++r) {
      gl_lds16(Ab + (size_t)srow[r] * lda + k0 + ssrc[r], As + (size_t)(r * 256 + tid) * 8);
      gl_lds16(Bb + (size_t)srow[r] * ldb + k0 + ssrc[r], Bs + (size_t)(r * 256 + tid) * 8);
    }
    __syncthreads();

#pragma unroll
    for (int kk = 0; kk < BK; kk += 16) {
      const int gr = (((kk >> 3) + hi) ^ rs) << 3;
      half8 af[2], bfr[2];
#pragma unroll
      for (int i = 0; i < 2; ++i)
        af[i] = *(const half8*)(As + (wm + i * 32 + l31) * BK + gr);
#pragma unroll
      for (int j = 0; j < 2; ++j)
        bfr[j] = *(const half8*)(Bs + (wn + j * 32 + l31) * BK + gr);
#pragma unroll
      for (int i = 0; i < 2; ++i)
#pragma unroll
        for (int j = 0; j < 2; ++j)
          acc[i][j] = __builtin_amdgcn_mfma_f32_32x32x16_f16(af[i], bfr[j], acc[i][j], 0, 0, 0);
    }
    __syncthreads();
  }

  // epilogue: repack through LDS (granule-swizzled), then 16B coalesced stores
  f16* Ch = Cout + (size_t)z * sC;
  f16* Ct = S;   // 128x128 f16 = 32 KiB
#pragma unroll
  for (int i = 0; i < 2; ++i)
#pragma unroll
    for (int j = 0; j < 2; ++j)
#pragma unroll
      for (int r = 0; r < 16; ++r) {
        const int rl = wm + i * 32 + (r & 3) + 8 * (r >> 2) + 4 * hi;
        const int cl = wn + j * 32 + l31;
        const float v = acc[i][j][r];
        f16 h;
        if constexpr (EPI == 0)      h = (f16)v;
        else if constexpr (EPI == 1) h = (f16)(v + bias[m0 + rl]);
        else if constexpr (EPI == 2) h = (f16)(v + bias[n0 + cl]);
        else                         h = (f16)(1.0f / (1.0f + __expf(-v)));
        Ct[rl * BN + ((((cl >> 3) ^ (rl & 7)) << 3) | (cl & 7))] = h;
      }
  __syncthreads();
#pragma unroll
  for (int p = 0; p < 8; ++p) {
    const int idx = p * 256 + tid;
    const int rl = idx >> 4;
    const int g  = idx & 15;
    half8 vv = *(const half8*)(Ct + rl * BN + ((g ^ (rl & 7)) << 3));
    *(half8*)(Ch + (size_t)(m0 + rl) * ldc + n0 + g * 8) = vv;
  }
}

// ---------------- weights f32->f16 + bias concat, one dispatch ----------------
__global__ __launch_bounds__(256)
void prep(const float* __restrict__ Wq, const float* __restrict__ Wk, const float* __restrict__ Wv,
          const float* __restrict__ bq, const float* __restrict__ bk,
          f16* __restrict__ WQKb, f16* __restrict__ Wvb, float* __restrict__ bqk)
{
  const int NV = CC * CC;
  const int NQ = DD * CC;
  int i = blockIdx.x * 256 + threadIdx.x;
  if (i < NV)                    Wvb[i] = (f16)Wv[i];
  else if (i < NV + NQ)          WQKb[i - NV] = (f16)Wq[i - NV];
  else if (i < NV + 2 * NQ)      WQKb[i - NV] = (f16)Wk[i - NV - NQ];
  else if (i < NV + 2 * NQ + 2 * DD) {
    int t = i - NV - 2 * NQ;
    bqk[t] = (t < DD) ? bq[t] : bk[t - DD];
  }
}

// ---------------- transpose + f32->f16 for x and x1 in one dispatch ----------------
__global__ __launch_bounds__(256)
void transpose_cvt(const float* __restrict__ x, const float* __restrict__ x1,
                   f16* __restrict__ ox, f16* __restrict__ ox1, int nb)
{
  const int zz = blockIdx.z;
  const int b  = (zz < nb) ? zz : zz - nb;
  const float* in = ((zz < nb) ? x : x1) + (size_t)b * CC * NNN;
  f16* out = ((zz < nb) ? ox : ox1) + (size_t)b * CC * NNN;
  __shared__ float tile[32][33];
  const int c0 = blockIdx.y * 32;
  const int n0 = blockIdx.x * 32;
  const int tx = threadIdx.x & 31;
  const int ty = threadIdx.x >> 5;
#pragma unroll
  for (int r = 0; r < 32; r += 8)
    tile[ty + r][tx] = in[(size_t)(c0 + ty + r) * NNN + n0 + tx];
  __syncthreads();
#pragma unroll
  for (int r = 0; r < 32; r += 8)
    out[(size_t)(n0 + ty + r) * CC + c0 + tx] = (f16)tile[tx][ty + r];
}

// ---------------- per-row mean + max (f16 input); grid (CC, nbatch) ----------------
__global__ __launch_bounds__(256)
void rowreduce(const f16* __restrict__ X, float* __restrict__ avg, float* __restrict__ mx, int ncols)
{
  const size_t ridx = (size_t)blockIdx.y * gridDim.x + blockIdx.x;
  const half8* p = (const half8*)(X + ridx * ncols);
  float s = 0.f, m = -3.402823466e38f;
  for (int i = threadIdx.x; i < ncols / 8; i += 256) {
    half8 v = p[i];
#pragma unroll
    for (int e = 0; e < 8; ++e) {
      float f = (float)v[e];
      s += f;
      m = fmaxf(m, f);
    }
  }
#pragma unroll
  for (int o = 32; o > 0; o >>= 1) {
    s += __shfl_down(s, o);
    m = fmaxf(m, __shfl_down(m, o));
  }
  __shared__ float ss[4], sm[4];
  if ((threadIdx.x & 63) == 0) { ss[threadIdx.x >> 6] = s; sm[threadIdx.x >> 6] = m; }
  __syncthreads();
  if (threadIdx.x == 0) {
    s = ss[0] + ss[1] + ss[2] + ss[3];
    m = fmaxf(fmaxf(sm[0], sm[1]), fmaxf(sm[2], sm[3]));
    avg[ridx] = s / (float)ncols;
    mx[ridx] = m;
  }
}

// ---------------- CBAM MLP gate; grid (nbatch) ----------------
__global__ __launch_bounds__(256)
void mlp_gate(const float* __restrict__ avg, const float* __restrict__ mxv,
              const float* __restrict__ W1, const float* __restrict__ W2,
              float* __restrict__ gate)
{
  const int z = blockIdx.x;
  avg += (size_t)z * CC; mxv += (size_t)z * CC; gate += (size_t)z * CC;
  const int t = threadIdx.x;
  const int r = t & 63;
  const int part = t >> 6;
  __shared__ float pa[4][64], pm[4][64], h[RRR];
  {
    const float* w = W1 + (size_t)r * CC + part * 256;
    const float* av = avg + part * 256;
    const float* mv = mxv + part * 256;
    float sa = 0.f, sm = 0.f;
    for (int c = 0; c < 256; ++c) { float wv = w[c]; sa += wv * av[c]; sm += wv * mv[c]; }
    pa[part][r] = sa; pm[part][r] = sm;
  }
  __syncthreads();
  if (t < RRR) {
    float A_ = pa[0][t] + pa[1][t] + pa[2][t] + pa[3][t];
    float M_ = pm[0][t] + pm[1][t] + pm[2][t] + pm[3][t];
    h[t] = fmaxf(A_, 0.f) + fmaxf(M_, 0.f);
  }
  __syncthreads();
  for (int c = t; c < CC; c += 256) {
    float s = 0.f;
    for (int rr = 0; rr < RRR; ++rr) s += W2[(size_t)c * RRR + rr] * h[rr];
    gate[c] = 1.0f / (1.0f + __expf(-s));
  }
}

// ---------------- apply gate: f16 in -> f32 out; grid (CC*NNN/8/256, nbatch) ----------------
__global__ __launch_bounds__(256)
void scale_out(const f16* __restrict__ oh, float* __restrict__ out, const float* __restrict__ gate)
{
  oh  += (size_t)blockIdx.y * CC * NNN;
  out += (size_t)blockIdx.y * CC * NNN;
  gate += (size_t)blockIdx.y * CC;
  size_t i = (size_t)blockIdx.x * 256 + threadIdx.x;   // over C*N/8
  half8 v = ((const half8*)oh)[i];
  const float g = gate[(i * 8) >> 12];                 // N = 4096
  float4 a = { (float)v[0] * g, (float)v[1] * g, (float)v[2] * g, (float)v[3] * g };
  float4 b = { (float)v[4] * g, (float)v[5] * g, (float)v[6] * g, (float)v[7] * g };
  float4* o = (float4*)out;
  o[2 * i]     = a;
  o[2 * i + 1] = b;
}

// ---------------- launch ----------------
extern "C" void kernel_launch(void* const* d_in, const int* in_sizes, int n_in,
                              void* d_out, int out_size, void* d_ws, size_t ws_size,
                              hipStream_t stream)
{
  const float* x    = (const float*)d_in[0];
  const float* x1   = (const float*)d_in[1];
  const float* Wq   = (const float*)d_in[2];
  const float* bq   = (const float*)d_in[3];
  const float* Wk   = (const float*)d_in[4];
  const float* bk   = (const float*)d_in[5];
  const float* Wv   = (const float*)d_in[6];
  const float* bv   = (const float*)d_in[7];
  const float* Wca1 = (const float*)d_in[8];
  const float* Wca2 = (const float*)d_in[9];
  float* out = (float*)d_out;

  char* ws = (char*)d_ws;
  size_t off = 0;
  auto alloc = [&](size_t bytes) { void* p = ws + off; off += (bytes + 255) & ~255ULL; return p; };

  f16* WQKb = (f16*)alloc((size_t)2 * DD * CC * 2);
  f16* Wvb  = (f16*)alloc((size_t)CC * CC * 2);
  float* bqk  = (float*)alloc(256 * 4);
  float* avg  = (float*)alloc((size_t)BBATCH * CC * 4);
  float* mxv  = (float*)alloc((size_t)BBATCH * CC * 4);
  float* gate = (float*)alloc((size_t)BBATCH * CC * 4);

  const size_t attB = (size_t)NNN * NNN * 2;              // 32 MiB / batch
  const size_t xTB  = (size_t)BBATCH * NNN * CC * 2;      // 32 MiB
  const size_t qkB  = (size_t)BBATCH * NNN * 2 * DD * 2;  // 8 MiB
  const size_t vBB  = (size_t)BBATCH * CC * NNN * 2;      // 32 MiB
  const size_t ohB  = (size_t)BBATCH * CC * NNN * 2;      // 32 MiB
  const size_t fixedEnd = off;

  int g = 0;
  for (int cand = BBATCH; cand >= 1; cand >>= 1) {
    size_t need = fixedEnd + 2 * xTB + qkB + vBB + ohB + (size_t)cand * attB + (1 << 20);
    if (need <= ws_size) { g = cand; break; }
  }

  const dim3 blk(256);
  const int prepN = CC * CC + 2 * DD * CC + 2 * DD;
  prep<<<(prepN + 255) / 256, blk, 0, stream>>>(Wq, Wk, Wv, bq, bk, WQKb, Wvb, bqk);

  if (g > 0) {
    f16* xTb  = (f16*)alloc(xTB);
    f16* x1Tb = (f16*)alloc(xTB);
    f16* QKt  = (f16*)alloc(qkB);     // [b][n][256] : 0..127 = Q, 128..255 = K
    f16* Vb   = (f16*)alloc(vBB);     // [b][c][m]
    f16* outh = (f16*)alloc(ohB);     // [b][c][n] f16
    f16* att  = (f16*)alloc((size_t)g * attB);

    transpose_cvt<<<dim3(NNN / 32, CC / 32, 2 * BBATCH), blk, 0, stream>>>(x, x1, xTb, x1Tb, BBATCH);

    gemm_bt<2><<<dim3(2 * DD / BN, NNN / BM, BBATCH), blk, 0, stream>>>(
        xTb, WQKb, QKt, bqk, 2 * DD, CC,
        CC, CC, 2 * DD, (size_t)NNN * CC, 0, (size_t)NNN * 2 * DD);
    gemm_bt<1><<<dim3(NNN / BN, CC / BM, BBATCH), blk, 0, stream>>>(
        Wvb, x1Tb, Vb, bv, NNN, CC,
        CC, CC, NNN, 0, (size_t)NNN * CC, (size_t)CC * NNN);

    for (int b0 = 0; b0 < BBATCH; b0 += g) {
      const int gc = (b0 + g <= BBATCH) ? g : (BBATCH - b0);
      const size_t sQK = (size_t)NNN * 2 * DD;
      gemm_bt<3><<<dim3(NNN / BN, NNN / BM, gc), blk, 0, stream>>>(
          QKt + (size_t)b0 * sQK, QKt + (size_t)b0 * sQK + DD, att, nullptr,
          NNN, DD, 2 * DD, 2 * DD, NNN, sQK, sQK, (size_t)NNN * NNN);
      gemm_bt<0><<<dim3(NNN / BN, CC / BM, gc), blk, 0, stream>>>(
          Vb + (size_t)b0 * CC * NNN, att, outh + (size_t)b0 * CC * NNN, nullptr,
          NNN, NNN, NNN, NNN, NNN,
          (size_t)CC * NNN, (size_t)NNN * NNN, (size_t)CC * NNN);
    }

    rowreduce<<<dim3(CC, BBATCH), blk, 0, stream>>>(outh, avg, mxv, NNN);
    mlp_gate<<<BBATCH, blk, 0, stream>>>(avg, mxv, Wca1, Wca2, gate);
    scale_out<<<dim3(CC * NNN / 8 / 256, BBATCH), blk, 0, stream>>>(outh, out, gate);
  } else {
    // legacy per-batch mode (ws-constrained fallback)
    f16* xTb  = (f16*)alloc((size_t)NNN * CC * 2);
    f16* x1Tb = (f16*)alloc((size_t)NNN * CC * 2);
    f16* QKt  = (f16*)alloc((size_t)NNN * 2 * DD * 2);
    f16* Vb   = (f16*)alloc((size_t)CC * NNN * 2);
    f16* outh = (f16*)alloc((size_t)CC * NNN * 2);
    f16* att  = (f16*)alloc(attB);

    for (int b = 0; b < BBATCH; ++b) {
      const float* xb  = x  + (size_t)b * CC * NNN;
      const float* x1b = x1 + (size_t)b * CC * NNN;
      float* outb = out + (size_t)b * CC * NNN;

      transpose_cvt<<<dim3(NNN / 32, CC / 32, 2), blk, 0, stream>>>(xb, x1b, xTb, x1Tb, 1);

      gemm_bt<2><<<dim3(2 * DD / BN, NNN / BM, 1), blk, 0, stream>>>(
          xTb, WQKb, QKt, bqk, 2 * DD, CC, CC, CC, 2 * DD, 0, 0, 0);
      gemm_bt<1><<<dim3(NNN / BN, CC / BM, 1), blk, 0, stream>>>(
          Wvb, x1Tb, Vb, bv, NNN, CC, CC, CC, NNN, 0, 0, 0);
      gemm_bt<3><<<dim3(NNN / BN, NNN / BM, 1), blk, 0, stream>>>(
          QKt, QKt + DD, att, nullptr, NNN, DD, 2 * DD, 2 * DD, NNN, 0, 0, 0);
      gemm_bt<0><<<dim3(NNN / BN, CC / BM, 1), blk, 0, stream>>>(
          Vb, att, outh, nullptr, NNN, NNN, NNN, NNN, NNN, 0, 0, 0);

      rowreduce<<<dim3(CC, 1), blk, 0, stream>>>(outh, avg + (size_t)b * CC, mxv + (size_t)b * CC, NNN);
      mlp_gate<<<1, blk, 0, stream>>>(avg + (size_t)b * CC, mxv + (size_t)b * CC, Wca1, Wca2, gate + (size_t)b * CC);
      scale_out<<<dim3(CC * NNN / 8 / 256, 1), blk, 0, stream>>>(outh, outb, gate + (size_t)b * CC);
    }
  }
}